// Round 12
// baseline (89.000 us; speedup 1.0000x reference)
//
#include <hip/hip_runtime.h>
#include <hip/hip_fp16.h>
#include <string.h>

#define B_ 2
#define C_ 4
#define H_ 512
#define W_ 512
#define V_ 100000
#define F_ 200000
#define A_ 8

#define HW_   (H_ * W_)                 // 262144 = 2^18
#define NPIX  (B_ * C_ * H_ * W_)       // 2,097,152
#define PLANE ((size_t)NPIX * 3)
#define PXB   512                       // pixels per block (2 per thread)

typedef float f32x4 __attribute__((ext_vector_type(4)));

__device__ __forceinline__ float2 unpack2f(double d) {
    float2 t;
    memcpy(&t, &d, 8);
    return t;
}

// ---------------------------------------------------------------------------
// Prep 1 (fused): fp16 face normals (B*F, 8B records) + faces64 pack (F)
// ---------------------------------------------------------------------------
__global__ void k_prep1(const float* __restrict__ vertex_pos,
                        const int* __restrict__ faces,
                        uint2* __restrict__ fn16,
                        unsigned long long* __restrict__ faces64) {
    int t = blockIdx.x * blockDim.x + threadIdx.x;
    if (t >= B_ * F_) return;
    int b = t / F_;
    int f = t - b * F_;
    int i0 = faces[f * 3 + 0];
    int i1 = faces[f * 3 + 1];
    int i2 = faces[f * 3 + 2];
    if (b == 0) {
        faces64[f] = (unsigned long long)(unsigned)i0 |
                     ((unsigned long long)(unsigned)i1 << 17) |
                     ((unsigned long long)(unsigned)i2 << 34);
    }
    const float* vp = vertex_pos + (size_t)b * V_ * 3;
    float p0x = vp[i0 * 3 + 0], p0y = vp[i0 * 3 + 1], p0z = vp[i0 * 3 + 2];
    float p1x = vp[i1 * 3 + 0], p1y = vp[i1 * 3 + 1], p1z = vp[i1 * 3 + 2];
    float p2x = vp[i2 * 3 + 0], p2y = vp[i2 * 3 + 1], p2z = vp[i2 * 3 + 2];
    float e1x = p1x - p0x, e1y = p1y - p0y, e1z = p1z - p0z;
    float e2x = p2x - p0x, e2y = p2y - p0y, e2z = p2z - p0z;
    float nx = e1y * e2z - e1z * e2y;
    float ny = e1z * e2x - e1x * e2z;
    float nz = e1x * e2y - e1y * e2x;
    __half2 h0 = __floats2half2_rn(nx, ny);
    __half2 h1 = __floats2half2_rn(nz, 0.f);
    fn16[t] = make_uint2(*reinterpret_cast<unsigned int*>(&h0),
                         *reinterpret_cast<unsigned int*>(&h1));
}

// ---------------------------------------------------------------------------
// Prep 2: one thread per (b,v).  Vertex normal from 8 fp16 fn gathers (b64),
// then 4 views x one 16B record:
//   rec16[bc*V+v] = { h2(px,py), h2(pz,nx), h2(ny,nz), h2(sx,sy) }
// (scr.z recomputed per-pixel: linear in blended pos since sum(bary)=1.)
// ---------------------------------------------------------------------------
__global__ void k_prep2(const float* __restrict__ vertex_pos,
                        const float* __restrict__ intrinsics,
                        const float* __restrict__ extrinsics,
                        const uint2* __restrict__ fn16,
                        const int* __restrict__ vert_adj_faces,
                        const float* __restrict__ vert_adj_weights,
                        uint4* __restrict__ rec16) {
    int t = blockIdx.x * blockDim.x + threadIdx.x;
    if (t >= B_ * V_) return;
    int b = t / V_;
    int v = t - b * V_;

    const int* adj = vert_adj_faces + (size_t)v * A_;
    const float* wt = vert_adj_weights + (size_t)v * A_;
    const uint2* fn = fn16 + (size_t)b * F_;
    float ax = 0.f, ay = 0.f, az = 0.f;
#pragma unroll
    for (int a = 0; a < A_; ++a) {
        uint2 r = fn[adj[a]];
        float w = wt[a];
        float2 n01 = __half22float2(*reinterpret_cast<__half2*>(&r.x));
        float2 n2  = __half22float2(*reinterpret_cast<__half2*>(&r.y));
        ax += w * n01.x;
        ay += w * n01.y;
        az += w * n2.x;
    }
    const float* p = vertex_pos + (size_t)t * 3;
    float x = p[0], y = p[1], z = p[2];
    __half2 hxy = __floats2half2_rn(x, y);
    __half2 hzn = __floats2half2_rn(z, ax);
    __half2 hnn = __floats2half2_rn(ay, az);
    unsigned int w0 = *reinterpret_cast<unsigned int*>(&hxy);
    unsigned int w1 = *reinterpret_cast<unsigned int*>(&hzn);
    unsigned int w2 = *reinterpret_cast<unsigned int*>(&hnn);

#pragma unroll
    for (int c = 0; c < C_; ++c) {
        int bc = b * C_ + c;
        const float* E = extrinsics + (size_t)bc * 12;
        float cv0 = x * E[0] + y * E[1] + z * E[2]  + E[3];
        float cv1 = x * E[4] + y * E[5] + z * E[6]  + E[7];
        float cv2 = x * E[8] + y * E[9] + z * E[10] + E[11];
        const float* K = intrinsics + (size_t)bc * 9;
        float i0 = cv0 * K[0] + cv1 * K[1] + cv2 * K[2];
        float i1 = cv0 * K[3] + cv1 * K[4] + cv2 * K[5];
        float i2 = cv0 * K[6] + cv1 * K[7] + cv2 * K[8];
        __half2 hs = __floats2half2_rn(i0 / i2, i1 / i2);
        rec16[(size_t)bc * V_ + v] =
            make_uint4(w0, w1, w2, *reinterpret_cast<unsigned int*>(&hs));
    }
}

// ---------------------------------------------------------------------------
// Pixel kernel: 2 px/thread, branchless always-gather (bg clamps to face 0,
// whose lines are wave-broadcast), batched load issue (2 waits/thread),
// double-buffered plane staging (6 syncs) + full-line cooperative NT stores.
// ---------------------------------------------------------------------------
__global__ __launch_bounds__(256, 8) void k_pixel(
        const unsigned long long* __restrict__ faces64,
        const float* __restrict__ inverse_extrinsics,
        const float* __restrict__ extrinsics,
        const int* __restrict__ face_id,
        const float* __restrict__ bary,
        const uint4* __restrict__ rec16,
        float* __restrict__ out) {
    __shared__ float lds[2][PXB * 3];   // 2 x 6144 B

    // 4096 blocks, 8 XCDs -> 512 contiguous blocks per XCD = one view
    int nb = gridDim.x;
    int bid = blockIdx.x;
    int swz = (bid & 7) * (nb >> 3) + (bid >> 3);
    int tid = threadIdx.x;

    int base = swz * PXB + tid * 2;     // first of 2 pixels
    int bc = base >> 18;                // HW_ = 2^18 (uniform per block)

    const float* ie = inverse_extrinsics + (size_t)bc * 16;
    float iw = ie[15];
    float ox = ie[3] / iw, oy = ie[7] / iw, oz = ie[11] / iw;
    const float* E = extrinsics + (size_t)bc * 12;
    float e8 = E[8], e9 = E[9], e10 = E[10], e11 = E[11];

    // streaming loads
    long long fid2 = __builtin_nontemporal_load((const long long*)(face_id + base));
    int f0 = (int)(fid2 & 0xFFFFFFFFll);
    int f1 = (int)(fid2 >> 32);
    float sel0 = (f0 >= 0) ? 1.f : 0.f;
    float sel1 = (f1 >= 0) ? 1.f : 0.f;
    int c0 = (f0 >= 0) ? f0 : 0;
    int c1 = (f1 >= 0) ? f1 : 0;

    // level-1 gathers: both faces64 issued together
    unsigned long long F0 = faces64[c0];
    unsigned long long F1 = faces64[c1];

    const double* bp = (const double*)(bary + (size_t)base * 3);
    float2 q0 = unpack2f(__builtin_nontemporal_load(bp + 0));
    float2 q1 = unpack2f(__builtin_nontemporal_load(bp + 1));
    float2 q2 = unpack2f(__builtin_nontemporal_load(bp + 2));

    // level-2 gathers: all 6 rec16 issued together
    size_t sbase = (size_t)bc * V_;
    uint4 A0 = rec16[sbase + (int)(F0 & 0x1FFFF)];
    uint4 B0 = rec16[sbase + (int)((F0 >> 17) & 0x1FFFF)];
    uint4 C0 = rec16[sbase + (int)((F0 >> 34) & 0x1FFFF)];
    uint4 A1 = rec16[sbase + (int)(F1 & 0x1FFFF)];
    uint4 B1 = rec16[sbase + (int)((F1 >> 17) & 0x1FFFF)];
    uint4 C1 = rec16[sbase + (int)((F1 >> 34) & 0x1FFFF)];

    float bw[2][3] = {{q0.x, q0.y, q1.x}, {q1.y, q2.x, q2.y}};
    float selv[2] = {sel0, sel1};
    const uint4* R[2][3] = {{&A0, &B0, &C0}, {&A1, &B1, &C1}};

    float fg[2], dep[2];
    float pos[2][3], nrm[2][3], sc[2][3];

#pragma unroll
    for (int k = 0; k < 2; ++k) {
        float w0 = bw[k][0], w1 = bw[k][1], w2 = bw[k][2];
        uint4 A = *R[k][0], Bv = *R[k][1], Cv = *R[k][2];

        float2 af0 = __half22float2(*reinterpret_cast<__half2*>(&A.x));
        float2 af1 = __half22float2(*reinterpret_cast<__half2*>(&A.y));
        float2 af2 = __half22float2(*reinterpret_cast<__half2*>(&A.z));
        float2 af3 = __half22float2(*reinterpret_cast<__half2*>(&A.w));
        float2 bf0 = __half22float2(*reinterpret_cast<__half2*>(&Bv.x));
        float2 bf1 = __half22float2(*reinterpret_cast<__half2*>(&Bv.y));
        float2 bf2 = __half22float2(*reinterpret_cast<__half2*>(&Bv.z));
        float2 bf3 = __half22float2(*reinterpret_cast<__half2*>(&Bv.w));
        float2 cf0 = __half22float2(*reinterpret_cast<__half2*>(&Cv.x));
        float2 cf1 = __half22float2(*reinterpret_cast<__half2*>(&Cv.y));
        float2 cf2 = __half22float2(*reinterpret_cast<__half2*>(&Cv.z));
        float2 cf3 = __half22float2(*reinterpret_cast<__half2*>(&Cv.w));

        float px = w0 * af0.x + w1 * bf0.x + w2 * cf0.x;
        float py = w0 * af0.y + w1 * bf0.y + w2 * cf0.y;
        float pz = w0 * af1.x + w1 * bf1.x + w2 * cf1.x;
        float nx = w0 * af1.y + w1 * bf1.y + w2 * cf1.y;
        float ny = w0 * af2.x + w1 * bf2.x + w2 * cf2.x;
        float nz = w0 * af2.y + w1 * bf2.y + w2 * cf2.y;
        float sx = w0 * af3.x + w1 * bf3.x + w2 * cf3.x;
        float sy = w0 * af3.y + w1 * bf3.y + w2 * cf3.y;
        float sz = e8 * px + e9 * py + e10 * pz + e11;

        float nlen = fmaxf(sqrtf(nx * nx + ny * ny + nz * nz), 1e-12f);
        nx /= nlen; ny /= nlen; nz /= nlen;

        float dx = ox - px, dy = oy - py, dz = oz - pz;
        float dd = sqrtf(dx * dx + dy * dy + dz * dz);

        float s = selv[k];
        fg[k] = s;
        dep[k] = s * dd;
        pos[k][0] = s * px; pos[k][1] = s * py; pos[k][2] = s * pz;
        nrm[k][0] = s * nx; nrm[k][1] = s * ny; nrm[k][2] = s * nz;
        sc[k][0] = s * sx; sc[k][1] = s * sy; sc[k][2] = s * sz;
    }

    // double-buffered plane staging: store(P) overlaps stage(P+1), 6 syncs
    const int CHUNKS = PXB * 3 / 4;     // 384 chunks of 16B
    size_t blockbase = (size_t)swz * (PXB * 3);

#define STAGE(BUF, V0, V1, V2, V3, V4, V5)                                      \
    {                                                                           \
        float* Lt = &lds[BUF][tid * 6];                                         \
        Lt[0] = (V0); Lt[1] = (V1); Lt[2] = (V2);                               \
        Lt[3] = (V3); Lt[4] = (V4); Lt[5] = (V5);                               \
    }
#define STORE(BUF, P)                                                           \
    {                                                                           \
        float* dst = out + (size_t)(P) * PLANE + blockbase;                     \
        for (int j = tid; j < CHUNKS; j += 256) {                               \
            f32x4 v = *(const f32x4*)&lds[BUF][j * 4];                          \
            __builtin_nontemporal_store(v, (f32x4*)dst + j);                    \
        }                                                                       \
    }

    STAGE(0, fg[0], fg[0], fg[0], fg[1], fg[1], fg[1])
    __syncthreads();
    STORE(0, 0)
    STAGE(1, pos[0][0], pos[0][1], pos[0][2], pos[1][0], pos[1][1], pos[1][2])
    __syncthreads();
    STORE(1, 1)
    STAGE(0, nrm[0][0], nrm[0][1], nrm[0][2], nrm[1][0], nrm[1][1], nrm[1][2])
    __syncthreads();
    STORE(0, 2)
    STAGE(1, dep[0], dep[0], dep[0], dep[1], dep[1], dep[1])
    __syncthreads();
    STORE(1, 3)
    STAGE(0, sc[0][0], sc[0][1], sc[0][2], sc[1][0], sc[1][1], sc[1][2])
    __syncthreads();
    STORE(0, 4)
#undef STAGE
#undef STORE
}

// ---------------------------------------------------------------------------
extern "C" void kernel_launch(void* const* d_in, const int* in_sizes, int n_in,
                              void* d_out, int out_size, void* d_ws, size_t ws_size,
                              hipStream_t stream) {
    const float* vertex_pos         = (const float*)d_in[0];
    const int*   faces              = (const int*)  d_in[1];
    const int*   vert_adj_faces     = (const int*)  d_in[2];
    const float* vert_adj_weights   = (const float*)d_in[3];
    const float* intrinsics         = (const float*)d_in[4];
    const float* extrinsics         = (const float*)d_in[5];
    const float* inverse_extrinsics = (const float*)d_in[6];
    const int*   face_id            = (const int*)  d_in[7];
    const float* barycentrics       = (const float*)d_in[8];
    float* out = (float*)d_out;
    char* ws = (char*)d_ws;
    const int TPB = 256;

    // layout: fn16 3.2MB | faces64 1.6MB | rec16 12.8MB = 17.6MB
    uint2*              fn16    = (uint2*)             (ws + 0);
    unsigned long long* faces64 = (unsigned long long*)(ws + 3200000);
    uint4*              rec16   = (uint4*)             (ws + 4800000);

    hipLaunchKernelGGL(k_prep1, dim3((B_ * F_ + TPB - 1) / TPB), dim3(TPB), 0, stream,
                       vertex_pos, faces, fn16, faces64);
    hipLaunchKernelGGL(k_prep2, dim3((B_ * V_ + TPB - 1) / TPB), dim3(TPB), 0, stream,
                       vertex_pos, intrinsics, extrinsics, fn16,
                       vert_adj_faces, vert_adj_weights, rec16);
    hipLaunchKernelGGL(k_pixel, dim3(NPIX / PXB), dim3(TPB), 0, stream,
                       faces64, inverse_extrinsics, extrinsics, face_id, barycentrics,
                       rec16, out);
}

// Round 13
// 80.544 us; speedup vs baseline: 1.1050x; 1.1050x over previous
//
#include <hip/hip_runtime.h>
#include <hip/hip_fp16.h>
#include <string.h>

#define B_ 2
#define C_ 4
#define H_ 512
#define W_ 512
#define V_ 100000
#define F_ 200000
#define A_ 8

#define HW_   (H_ * W_)                 // 262144 = 2^18
#define NPIX  (B_ * C_ * H_ * W_)       // 2,097,152
#define PLANE ((size_t)NPIX * 3)
#define PXB   512                       // pixels per block (2 per thread)

typedef float f32x4 __attribute__((ext_vector_type(4)));

__device__ __forceinline__ float2 unpack2f(double d) {
    float2 t;
    memcpy(&t, &d, 8);
    return t;
}

// ---------------------------------------------------------------------------
// Prep 1 (fused): fp16 face normals (B*F, 8B records) + faces64 pack (F)
// ---------------------------------------------------------------------------
__global__ void k_prep1(const float* __restrict__ vertex_pos,
                        const int* __restrict__ faces,
                        uint2* __restrict__ fn16,
                        unsigned long long* __restrict__ faces64) {
    int t = blockIdx.x * blockDim.x + threadIdx.x;
    if (t >= B_ * F_) return;
    int b = t / F_;
    int f = t - b * F_;
    int i0 = faces[f * 3 + 0];
    int i1 = faces[f * 3 + 1];
    int i2 = faces[f * 3 + 2];
    if (b == 0) {
        faces64[f] = (unsigned long long)(unsigned)i0 |
                     ((unsigned long long)(unsigned)i1 << 17) |
                     ((unsigned long long)(unsigned)i2 << 34);
    }
    const float* vp = vertex_pos + (size_t)b * V_ * 3;
    float p0x = vp[i0 * 3 + 0], p0y = vp[i0 * 3 + 1], p0z = vp[i0 * 3 + 2];
    float p1x = vp[i1 * 3 + 0], p1y = vp[i1 * 3 + 1], p1z = vp[i1 * 3 + 2];
    float p2x = vp[i2 * 3 + 0], p2y = vp[i2 * 3 + 1], p2z = vp[i2 * 3 + 2];
    float e1x = p1x - p0x, e1y = p1y - p0y, e1z = p1z - p0z;
    float e2x = p2x - p0x, e2y = p2y - p0y, e2z = p2z - p0z;
    float nx = e1y * e2z - e1z * e2y;
    float ny = e1z * e2x - e1x * e2z;
    float nz = e1x * e2y - e1y * e2x;
    __half2 h0 = __floats2half2_rn(nx, ny);
    __half2 h1 = __floats2half2_rn(nz, 0.f);
    fn16[t] = make_uint2(*reinterpret_cast<unsigned int*>(&h0),
                         *reinterpret_cast<unsigned int*>(&h1));
}

// ---------------------------------------------------------------------------
// Prep 2: one thread per (b,v).  Vertex normal from 8 fp16 fn gathers (b64),
// then 4 views x one 16B record:
//   rec16[bc*V+v] = { h2(px,py), h2(pz,nx), h2(ny,nz), h2(sx,sy) }
// (scr.z recomputed per-pixel: linear in blended pos since sum(bary)=1.)
// ---------------------------------------------------------------------------
__global__ void k_prep2(const float* __restrict__ vertex_pos,
                        const float* __restrict__ intrinsics,
                        const float* __restrict__ extrinsics,
                        const uint2* __restrict__ fn16,
                        const int* __restrict__ vert_adj_faces,
                        const float* __restrict__ vert_adj_weights,
                        uint4* __restrict__ rec16) {
    int t = blockIdx.x * blockDim.x + threadIdx.x;
    if (t >= B_ * V_) return;
    int b = t / V_;
    int v = t - b * V_;

    const int* adj = vert_adj_faces + (size_t)v * A_;
    const float* wt = vert_adj_weights + (size_t)v * A_;
    const uint2* fn = fn16 + (size_t)b * F_;
    float ax = 0.f, ay = 0.f, az = 0.f;
#pragma unroll
    for (int a = 0; a < A_; ++a) {
        uint2 r = fn[adj[a]];
        float w = wt[a];
        float2 n01 = __half22float2(*reinterpret_cast<__half2*>(&r.x));
        float2 n2  = __half22float2(*reinterpret_cast<__half2*>(&r.y));
        ax += w * n01.x;
        ay += w * n01.y;
        az += w * n2.x;
    }
    const float* p = vertex_pos + (size_t)t * 3;
    float x = p[0], y = p[1], z = p[2];
    __half2 hxy = __floats2half2_rn(x, y);
    __half2 hzn = __floats2half2_rn(z, ax);
    __half2 hnn = __floats2half2_rn(ay, az);
    unsigned int w0 = *reinterpret_cast<unsigned int*>(&hxy);
    unsigned int w1 = *reinterpret_cast<unsigned int*>(&hzn);
    unsigned int w2 = *reinterpret_cast<unsigned int*>(&hnn);

#pragma unroll
    for (int c = 0; c < C_; ++c) {
        int bc = b * C_ + c;
        const float* E = extrinsics + (size_t)bc * 12;
        float cv0 = x * E[0] + y * E[1] + z * E[2]  + E[3];
        float cv1 = x * E[4] + y * E[5] + z * E[6]  + E[7];
        float cv2 = x * E[8] + y * E[9] + z * E[10] + E[11];
        const float* K = intrinsics + (size_t)bc * 9;
        float i0 = cv0 * K[0] + cv1 * K[1] + cv2 * K[2];
        float i1 = cv0 * K[3] + cv1 * K[4] + cv2 * K[5];
        float i2 = cv0 * K[6] + cv1 * K[7] + cv2 * K[8];
        __half2 hs = __floats2half2_rn(i0 / i2, i1 / i2);
        rec16[(size_t)bc * V_ + v] =
            make_uint4(w0, w1, w2, *reinterpret_cast<unsigned int*>(&hs));
    }
}

// ---------------------------------------------------------------------------
// Pixel kernel (r11 structure): 2 px/thread, branched per-pixel gathers
// (short VGPR live ranges), XCD swizzle, 4 gathers/px.  Output via
// double-buffered plane staging: store(P) overlaps stage(P+1), 6 syncs,
// full-line cooperative NT stores.  LDS 12.3KB -> 8 blocks/CU.
// ---------------------------------------------------------------------------
__global__ __launch_bounds__(256, 8) void k_pixel(
        const unsigned long long* __restrict__ faces64,
        const float* __restrict__ inverse_extrinsics,
        const float* __restrict__ extrinsics,
        const int* __restrict__ face_id,
        const float* __restrict__ bary,
        const uint4* __restrict__ rec16,
        float* __restrict__ out) {
    __shared__ float lds[2][PXB * 3];   // 2 x 6144 B

    // 4096 blocks, 8 XCDs -> 512 contiguous blocks per XCD = one view
    int nb = gridDim.x;
    int bid = blockIdx.x;
    int swz = (bid & 7) * (nb >> 3) + (bid >> 3);
    int tid = threadIdx.x;

    int base = swz * PXB + tid * 2;     // first of 2 pixels
    int bc = base >> 18;                // HW_ = 2^18 (uniform per block)

    const float* ie = inverse_extrinsics + (size_t)bc * 16;
    float iw = ie[15];
    float ox = ie[3] / iw, oy = ie[7] / iw, oz = ie[11] / iw;
    const float* E = extrinsics + (size_t)bc * 12;
    float e8 = E[8], e9 = E[9], e10 = E[10], e11 = E[11];

    long long fid2 = __builtin_nontemporal_load((const long long*)(face_id + base));
    int fidv[2] = { (int)(fid2 & 0xFFFFFFFFll), (int)(fid2 >> 32) };

    const double* bp = (const double*)(bary + (size_t)base * 3);
    float2 q0 = unpack2f(__builtin_nontemporal_load(bp + 0));
    float2 q1 = unpack2f(__builtin_nontemporal_load(bp + 1));
    float2 q2 = unpack2f(__builtin_nontemporal_load(bp + 2));
    float bw[2][3] = {{q0.x, q0.y, q1.x}, {q1.y, q2.x, q2.y}};

    float fg[2], dep[2];
    float pos[2][3], nrm[2][3], sc[2][3];

#pragma unroll
    for (int k = 0; k < 2; ++k) {
        int fid = fidv[k];
        float w0 = bw[k][0], w1 = bw[k][1], w2 = bw[k][2];
        if (fid >= 0) {
            unsigned long long f3 = faces64[fid];
            int i0 = (int)(f3 & 0x1FFFF);
            int i1 = (int)((f3 >> 17) & 0x1FFFF);
            int i2 = (int)((f3 >> 34) & 0x1FFFF);

            size_t sbase = (size_t)bc * V_;
            uint4 A  = rec16[sbase + i0];
            uint4 Bv = rec16[sbase + i1];
            uint4 Cv = rec16[sbase + i2];

            float2 af0 = __half22float2(*reinterpret_cast<__half2*>(&A.x));
            float2 af1 = __half22float2(*reinterpret_cast<__half2*>(&A.y));
            float2 af2 = __half22float2(*reinterpret_cast<__half2*>(&A.z));
            float2 af3 = __half22float2(*reinterpret_cast<__half2*>(&A.w));
            float2 bf0 = __half22float2(*reinterpret_cast<__half2*>(&Bv.x));
            float2 bf1 = __half22float2(*reinterpret_cast<__half2*>(&Bv.y));
            float2 bf2 = __half22float2(*reinterpret_cast<__half2*>(&Bv.z));
            float2 bf3 = __half22float2(*reinterpret_cast<__half2*>(&Bv.w));
            float2 cf0 = __half22float2(*reinterpret_cast<__half2*>(&Cv.x));
            float2 cf1 = __half22float2(*reinterpret_cast<__half2*>(&Cv.y));
            float2 cf2 = __half22float2(*reinterpret_cast<__half2*>(&Cv.z));
            float2 cf3 = __half22float2(*reinterpret_cast<__half2*>(&Cv.w));

            float px = w0 * af0.x + w1 * bf0.x + w2 * cf0.x;
            float py = w0 * af0.y + w1 * bf0.y + w2 * cf0.y;
            float pz = w0 * af1.x + w1 * bf1.x + w2 * cf1.x;
            float nx = w0 * af1.y + w1 * bf1.y + w2 * cf1.y;
            float ny = w0 * af2.x + w1 * bf2.x + w2 * cf2.x;
            float nz = w0 * af2.y + w1 * bf2.y + w2 * cf2.y;
            float sx = w0 * af3.x + w1 * bf3.x + w2 * cf3.x;
            float sy = w0 * af3.y + w1 * bf3.y + w2 * cf3.y;
            float sz = e8 * px + e9 * py + e10 * pz + e11;

            float nlen = fmaxf(sqrtf(nx * nx + ny * ny + nz * nz), 1e-12f);
            nx /= nlen; ny /= nlen; nz /= nlen;

            float dx = ox - px, dy = oy - py, dz = oz - pz;
            fg[k] = 1.f;
            dep[k] = sqrtf(dx * dx + dy * dy + dz * dz);
            pos[k][0] = px; pos[k][1] = py; pos[k][2] = pz;
            nrm[k][0] = nx; nrm[k][1] = ny; nrm[k][2] = nz;
            sc[k][0] = sx; sc[k][1] = sy; sc[k][2] = sz;
        } else {
            fg[k] = 0.f; dep[k] = 0.f;
            pos[k][0] = pos[k][1] = pos[k][2] = 0.f;
            nrm[k][0] = nrm[k][1] = nrm[k][2] = 0.f;
            sc[k][0] = sc[k][1] = sc[k][2] = 0.f;
        }
    }

    // double-buffered plane staging: store(P) overlaps stage(P+1), 6 syncs
    const int CHUNKS = PXB * 3 / 4;     // 384 chunks of 16B
    size_t blockbase = (size_t)swz * (PXB * 3);

#define STAGE(BUF, V0, V1, V2, V3, V4, V5)                                      \
    {                                                                           \
        float* Lt = &lds[BUF][tid * 6];                                         \
        Lt[0] = (V0); Lt[1] = (V1); Lt[2] = (V2);                               \
        Lt[3] = (V3); Lt[4] = (V4); Lt[5] = (V5);                               \
    }
#define STORE(BUF, P)                                                           \
    {                                                                           \
        float* dst = out + (size_t)(P) * PLANE + blockbase;                     \
        for (int j = tid; j < CHUNKS; j += 256) {                               \
            f32x4 v = *(const f32x4*)&lds[BUF][j * 4];                          \
            __builtin_nontemporal_store(v, (f32x4*)dst + j);                    \
        }                                                                       \
    }

    STAGE(0, fg[0], fg[0], fg[0], fg[1], fg[1], fg[1])
    __syncthreads();
    STORE(0, 0)
    STAGE(1, pos[0][0], pos[0][1], pos[0][2], pos[1][0], pos[1][1], pos[1][2])
    __syncthreads();
    STORE(1, 1)
    STAGE(0, nrm[0][0], nrm[0][1], nrm[0][2], nrm[1][0], nrm[1][1], nrm[1][2])
    __syncthreads();
    STORE(0, 2)
    STAGE(1, dep[0], dep[0], dep[0], dep[1], dep[1], dep[1])
    __syncthreads();
    STORE(1, 3)
    STAGE(0, sc[0][0], sc[0][1], sc[0][2], sc[1][0], sc[1][1], sc[1][2])
    __syncthreads();
    STORE(0, 4)
#undef STAGE
#undef STORE
}

// ---------------------------------------------------------------------------
extern "C" void kernel_launch(void* const* d_in, const int* in_sizes, int n_in,
                              void* d_out, int out_size, void* d_ws, size_t ws_size,
                              hipStream_t stream) {
    const float* vertex_pos         = (const float*)d_in[0];
    const int*   faces              = (const int*)  d_in[1];
    const int*   vert_adj_faces     = (const int*)  d_in[2];
    const float* vert_adj_weights   = (const float*)d_in[3];
    const float* intrinsics         = (const float*)d_in[4];
    const float* extrinsics         = (const float*)d_in[5];
    const float* inverse_extrinsics = (const float*)d_in[6];
    const int*   face_id            = (const int*)  d_in[7];
    const float* barycentrics       = (const float*)d_in[8];
    float* out = (float*)d_out;
    char* ws = (char*)d_ws;
    const int TPB = 256;

    // layout: fn16 3.2MB | faces64 1.6MB | rec16 12.8MB = 17.6MB
    uint2*              fn16    = (uint2*)             (ws + 0);
    unsigned long long* faces64 = (unsigned long long*)(ws + 3200000);
    uint4*              rec16   = (uint4*)             (ws + 4800000);

    hipLaunchKernelGGL(k_prep1, dim3((B_ * F_ + TPB - 1) / TPB), dim3(TPB), 0, stream,
                       vertex_pos, faces, fn16, faces64);
    hipLaunchKernelGGL(k_prep2, dim3((B_ * V_ + TPB - 1) / TPB), dim3(TPB), 0, stream,
                       vertex_pos, intrinsics, extrinsics, fn16,
                       vert_adj_faces, vert_adj_weights, rec16);
    hipLaunchKernelGGL(k_pixel, dim3(NPIX / PXB), dim3(TPB), 0, stream,
                       faces64, inverse_extrinsics, extrinsics, face_id, barycentrics,
                       rec16, out);
}

// Round 14
// 80.159 us; speedup vs baseline: 1.1103x; 1.0048x over previous
//
#include <hip/hip_runtime.h>
#include <hip/hip_fp16.h>
#include <string.h>

#define B_ 2
#define C_ 4
#define H_ 512
#define W_ 512
#define V_ 100000
#define F_ 200000
#define A_ 8

#define HW_   (H_ * W_)                 // 262144 = 2^18
#define NPIX  (B_ * C_ * H_ * W_)       // 2,097,152
#define PLANE ((size_t)NPIX * 3)
#define PXB   512                       // pixels per block (2 per thread)

typedef float f32x4 __attribute__((ext_vector_type(4)));

__device__ __forceinline__ float2 unpack2f(double d) {
    float2 t;
    memcpy(&t, &d, 8);
    return t;
}

// ---------------------------------------------------------------------------
// Prep 1 (fused): fp16 face normals (B*F, 8B records) + faces64 pack (F)
// ---------------------------------------------------------------------------
__global__ void k_prep1(const float* __restrict__ vertex_pos,
                        const int* __restrict__ faces,
                        uint2* __restrict__ fn16,
                        unsigned long long* __restrict__ faces64) {
    int t = blockIdx.x * blockDim.x + threadIdx.x;
    if (t >= B_ * F_) return;
    int b = t / F_;
    int f = t - b * F_;
    int i0 = faces[f * 3 + 0];
    int i1 = faces[f * 3 + 1];
    int i2 = faces[f * 3 + 2];
    if (b == 0) {
        faces64[f] = (unsigned long long)(unsigned)i0 |
                     ((unsigned long long)(unsigned)i1 << 17) |
                     ((unsigned long long)(unsigned)i2 << 34);
    }
    const float* vp = vertex_pos + (size_t)b * V_ * 3;
    float p0x = vp[i0 * 3 + 0], p0y = vp[i0 * 3 + 1], p0z = vp[i0 * 3 + 2];
    float p1x = vp[i1 * 3 + 0], p1y = vp[i1 * 3 + 1], p1z = vp[i1 * 3 + 2];
    float p2x = vp[i2 * 3 + 0], p2y = vp[i2 * 3 + 1], p2z = vp[i2 * 3 + 2];
    float e1x = p1x - p0x, e1y = p1y - p0y, e1z = p1z - p0z;
    float e2x = p2x - p0x, e2y = p2y - p0y, e2z = p2z - p0z;
    float nx = e1y * e2z - e1z * e2y;
    float ny = e1z * e2x - e1x * e2z;
    float nz = e1x * e2y - e1y * e2x;
    __half2 h0 = __floats2half2_rn(nx, ny);
    __half2 h1 = __floats2half2_rn(nz, 0.f);
    fn16[t] = make_uint2(*reinterpret_cast<unsigned int*>(&h0),
                         *reinterpret_cast<unsigned int*>(&h1));
}

// ---------------------------------------------------------------------------
// Prep 2: one thread per (b,v).  Vertex normal from 8 fp16 fn gathers (b64),
// then 4 views x one 16B record:
//   rec16[bc*V+v] = { h2(px,py), h2(pz,nx), h2(ny,nz), h2(sx,sy) }
// (scr.z recomputed per-pixel: linear in blended pos since sum(bary)=1.)
// ---------------------------------------------------------------------------
__global__ void k_prep2(const float* __restrict__ vertex_pos,
                        const float* __restrict__ intrinsics,
                        const float* __restrict__ extrinsics,
                        const uint2* __restrict__ fn16,
                        const int* __restrict__ vert_adj_faces,
                        const float* __restrict__ vert_adj_weights,
                        uint4* __restrict__ rec16) {
    int t = blockIdx.x * blockDim.x + threadIdx.x;
    if (t >= B_ * V_) return;
    int b = t / V_;
    int v = t - b * V_;

    const int* adj = vert_adj_faces + (size_t)v * A_;
    const float* wt = vert_adj_weights + (size_t)v * A_;
    const uint2* fn = fn16 + (size_t)b * F_;
    float ax = 0.f, ay = 0.f, az = 0.f;
#pragma unroll
    for (int a = 0; a < A_; ++a) {
        uint2 r = fn[adj[a]];
        float w = wt[a];
        float2 n01 = __half22float2(*reinterpret_cast<__half2*>(&r.x));
        float2 n2  = __half22float2(*reinterpret_cast<__half2*>(&r.y));
        ax += w * n01.x;
        ay += w * n01.y;
        az += w * n2.x;
    }
    const float* p = vertex_pos + (size_t)t * 3;
    float x = p[0], y = p[1], z = p[2];
    __half2 hxy = __floats2half2_rn(x, y);
    __half2 hzn = __floats2half2_rn(z, ax);
    __half2 hnn = __floats2half2_rn(ay, az);
    unsigned int w0 = *reinterpret_cast<unsigned int*>(&hxy);
    unsigned int w1 = *reinterpret_cast<unsigned int*>(&hzn);
    unsigned int w2 = *reinterpret_cast<unsigned int*>(&hnn);

#pragma unroll
    for (int c = 0; c < C_; ++c) {
        int bc = b * C_ + c;
        const float* E = extrinsics + (size_t)bc * 12;
        float cv0 = x * E[0] + y * E[1] + z * E[2]  + E[3];
        float cv1 = x * E[4] + y * E[5] + z * E[6]  + E[7];
        float cv2 = x * E[8] + y * E[9] + z * E[10] + E[11];
        const float* K = intrinsics + (size_t)bc * 9;
        float i0 = cv0 * K[0] + cv1 * K[1] + cv2 * K[2];
        float i1 = cv0 * K[3] + cv1 * K[4] + cv2 * K[5];
        float i2 = cv0 * K[6] + cv1 * K[7] + cv2 * K[8];
        __half2 hs = __floats2half2_rn(i0 / i2, i1 / i2);
        rec16[(size_t)bc * V_ + v] =
            make_uint4(w0, w1, w2, *reinterpret_cast<unsigned int*>(&hs));
    }
}

// ---------------------------------------------------------------------------
// Pixel kernel: 2 px/thread.  Level-1 (faces64) gathers for BOTH pixels are
// hoisted and issued back-to-back with clamped indices (bg -> face 0, whose
// lines are wave-broadcast); level-2 rec16 gathers + compute stay branched
// per pixel (short VGPR live ranges).  Double-buffered plane staging with
// full-line cooperative NT stores.  LDS 12.3KB -> 8 blocks/CU.
// ---------------------------------------------------------------------------
__global__ __launch_bounds__(256, 8) void k_pixel(
        const unsigned long long* __restrict__ faces64,
        const float* __restrict__ inverse_extrinsics,
        const float* __restrict__ extrinsics,
        const int* __restrict__ face_id,
        const float* __restrict__ bary,
        const uint4* __restrict__ rec16,
        float* __restrict__ out) {
    __shared__ float lds[2][PXB * 3];   // 2 x 6144 B

    // 4096 blocks, 8 XCDs -> 512 contiguous blocks per XCD = one view
    int nb = gridDim.x;
    int bid = blockIdx.x;
    int swz = (bid & 7) * (nb >> 3) + (bid >> 3);
    int tid = threadIdx.x;

    int base = swz * PXB + tid * 2;     // first of 2 pixels
    int bc = base >> 18;                // HW_ = 2^18 (uniform per block)

    const float* ie = inverse_extrinsics + (size_t)bc * 16;
    float iw = ie[15];
    float ox = ie[3] / iw, oy = ie[7] / iw, oz = ie[11] / iw;
    const float* E = extrinsics + (size_t)bc * 12;
    float e8 = E[8], e9 = E[9], e10 = E[10], e11 = E[11];

    long long fid2 = __builtin_nontemporal_load((const long long*)(face_id + base));
    int f0 = (int)(fid2 & 0xFFFFFFFFll);
    int f1 = (int)(fid2 >> 32);

    // level-1: both faces64 gathers issued back-to-back (clamped indices;
    // background lanes read face 0 -> wave-broadcast line, ~free)
    unsigned long long F3[2];
    F3[0] = faces64[f0 >= 0 ? f0 : 0];
    F3[1] = faces64[f1 >= 0 ? f1 : 0];
    int fidv[2] = {f0, f1};

    const double* bp = (const double*)(bary + (size_t)base * 3);
    float2 q0 = unpack2f(__builtin_nontemporal_load(bp + 0));
    float2 q1 = unpack2f(__builtin_nontemporal_load(bp + 1));
    float2 q2 = unpack2f(__builtin_nontemporal_load(bp + 2));
    float bw[2][3] = {{q0.x, q0.y, q1.x}, {q1.y, q2.x, q2.y}};

    float fg[2], dep[2];
    float pos[2][3], nrm[2][3], sc[2][3];

#pragma unroll
    for (int k = 0; k < 2; ++k) {
        float w0 = bw[k][0], w1 = bw[k][1], w2 = bw[k][2];
        if (fidv[k] >= 0) {
            unsigned long long f3 = F3[k];
            int i0 = (int)(f3 & 0x1FFFF);
            int i1 = (int)((f3 >> 17) & 0x1FFFF);
            int i2 = (int)((f3 >> 34) & 0x1FFFF);

            size_t sbase = (size_t)bc * V_;
            uint4 A  = rec16[sbase + i0];
            uint4 Bv = rec16[sbase + i1];
            uint4 Cv = rec16[sbase + i2];

            float2 af0 = __half22float2(*reinterpret_cast<__half2*>(&A.x));
            float2 af1 = __half22float2(*reinterpret_cast<__half2*>(&A.y));
            float2 af2 = __half22float2(*reinterpret_cast<__half2*>(&A.z));
            float2 af3 = __half22float2(*reinterpret_cast<__half2*>(&A.w));
            float2 bf0 = __half22float2(*reinterpret_cast<__half2*>(&Bv.x));
            float2 bf1 = __half22float2(*reinterpret_cast<__half2*>(&Bv.y));
            float2 bf2 = __half22float2(*reinterpret_cast<__half2*>(&Bv.z));
            float2 bf3 = __half22float2(*reinterpret_cast<__half2*>(&Bv.w));
            float2 cf0 = __half22float2(*reinterpret_cast<__half2*>(&Cv.x));
            float2 cf1 = __half22float2(*reinterpret_cast<__half2*>(&Cv.y));
            float2 cf2 = __half22float2(*reinterpret_cast<__half2*>(&Cv.z));
            float2 cf3 = __half22float2(*reinterpret_cast<__half2*>(&Cv.w));

            float px = w0 * af0.x + w1 * bf0.x + w2 * cf0.x;
            float py = w0 * af0.y + w1 * bf0.y + w2 * cf0.y;
            float pz = w0 * af1.x + w1 * bf1.x + w2 * cf1.x;
            float nx = w0 * af1.y + w1 * bf1.y + w2 * cf1.y;
            float ny = w0 * af2.x + w1 * bf2.x + w2 * cf2.x;
            float nz = w0 * af2.y + w1 * bf2.y + w2 * cf2.y;
            float sx = w0 * af3.x + w1 * bf3.x + w2 * cf3.x;
            float sy = w0 * af3.y + w1 * bf3.y + w2 * cf3.y;
            float sz = e8 * px + e9 * py + e10 * pz + e11;

            float nlen = fmaxf(sqrtf(nx * nx + ny * ny + nz * nz), 1e-12f);
            nx /= nlen; ny /= nlen; nz /= nlen;

            float dx = ox - px, dy = oy - py, dz = oz - pz;
            fg[k] = 1.f;
            dep[k] = sqrtf(dx * dx + dy * dy + dz * dz);
            pos[k][0] = px; pos[k][1] = py; pos[k][2] = pz;
            nrm[k][0] = nx; nrm[k][1] = ny; nrm[k][2] = nz;
            sc[k][0] = sx; sc[k][1] = sy; sc[k][2] = sz;
        } else {
            fg[k] = 0.f; dep[k] = 0.f;
            pos[k][0] = pos[k][1] = pos[k][2] = 0.f;
            nrm[k][0] = nrm[k][1] = nrm[k][2] = 0.f;
            sc[k][0] = sc[k][1] = sc[k][2] = 0.f;
        }
    }

    // double-buffered plane staging: store(P) overlaps stage(P+1), 6 syncs
    const int CHUNKS = PXB * 3 / 4;     // 384 chunks of 16B
    size_t blockbase = (size_t)swz * (PXB * 3);

#define STAGE(BUF, V0, V1, V2, V3, V4, V5)                                      \
    {                                                                           \
        float* Lt = &lds[BUF][tid * 6];                                         \
        Lt[0] = (V0); Lt[1] = (V1); Lt[2] = (V2);                               \
        Lt[3] = (V3); Lt[4] = (V4); Lt[5] = (V5);                               \
    }
#define STORE(BUF, P)                                                           \
    {                                                                           \
        float* dst = out + (size_t)(P) * PLANE + blockbase;                     \
        for (int j = tid; j < CHUNKS; j += 256) {                               \
            f32x4 v = *(const f32x4*)&lds[BUF][j * 4];                          \
            __builtin_nontemporal_store(v, (f32x4*)dst + j);                    \
        }                                                                       \
    }

    STAGE(0, fg[0], fg[0], fg[0], fg[1], fg[1], fg[1])
    __syncthreads();
    STORE(0, 0)
    STAGE(1, pos[0][0], pos[0][1], pos[0][2], pos[1][0], pos[1][1], pos[1][2])
    __syncthreads();
    STORE(1, 1)
    STAGE(0, nrm[0][0], nrm[0][1], nrm[0][2], nrm[1][0], nrm[1][1], nrm[1][2])
    __syncthreads();
    STORE(0, 2)
    STAGE(1, dep[0], dep[0], dep[0], dep[1], dep[1], dep[1])
    __syncthreads();
    STORE(1, 3)
    STAGE(0, sc[0][0], sc[0][1], sc[0][2], sc[1][0], sc[1][1], sc[1][2])
    __syncthreads();
    STORE(0, 4)
#undef STAGE
#undef STORE
}

// ---------------------------------------------------------------------------
extern "C" void kernel_launch(void* const* d_in, const int* in_sizes, int n_in,
                              void* d_out, int out_size, void* d_ws, size_t ws_size,
                              hipStream_t stream) {
    const float* vertex_pos         = (const float*)d_in[0];
    const int*   faces              = (const int*)  d_in[1];
    const int*   vert_adj_faces     = (const int*)  d_in[2];
    const float* vert_adj_weights   = (const float*)d_in[3];
    const float* intrinsics         = (const float*)d_in[4];
    const float* extrinsics         = (const float*)d_in[5];
    const float* inverse_extrinsics = (const float*)d_in[6];
    const int*   face_id            = (const int*)  d_in[7];
    const float* barycentrics       = (const float*)d_in[8];
    float* out = (float*)d_out;
    char* ws = (char*)d_ws;
    const int TPB = 256;

    // layout: fn16 3.2MB | faces64 1.6MB | rec16 12.8MB = 17.6MB
    uint2*              fn16    = (uint2*)             (ws + 0);
    unsigned long long* faces64 = (unsigned long long*)(ws + 3200000);
    uint4*              rec16   = (uint4*)             (ws + 4800000);

    hipLaunchKernelGGL(k_prep1, dim3((B_ * F_ + TPB - 1) / TPB), dim3(TPB), 0, stream,
                       vertex_pos, faces, fn16, faces64);
    hipLaunchKernelGGL(k_prep2, dim3((B_ * V_ + TPB - 1) / TPB), dim3(TPB), 0, stream,
                       vertex_pos, intrinsics, extrinsics, fn16,
                       vert_adj_faces, vert_adj_weights, rec16);
    hipLaunchKernelGGL(k_pixel, dim3(NPIX / PXB), dim3(TPB), 0, stream,
                       faces64, inverse_extrinsics, extrinsics, face_id, barycentrics,
                       rec16, out);
}